// Round 2
// baseline (1316.267 us; speedup 1.0000x reference)
//
#include <hip/hip_runtime.h>
#include <math.h>

#define N_NODES 100000
#define N_EDGES 1600000
#define E_TOT   (N_EDGES + N_NODES)
#define IN_DIM  256
#define HID     128
#define OUT_DIM 64
#define NEG_SLOPE 0.2f

// ---------------- CSR build ----------------

__global__ void count_kernel(const int* __restrict__ ei, int* __restrict__ counts) {
    int e = blockIdx.x * blockDim.x + threadIdx.x;
    if (e >= E_TOT) return;
    int dst = (e < N_EDGES) ? ei[N_EDGES + e] : (e - N_EDGES);
    atomicAdd(&counts[dst], 1);
}

// single block, 1024 threads: exclusive scan of counts -> row_start, and
// re-init counts[] as the scatter cursor.
__global__ __launch_bounds__(1024)
void scan_kernel(int* __restrict__ counts, int* __restrict__ row_start) {
    __shared__ int lds[1024];
    int t = threadIdx.x;
    const int CH = (N_NODES + 1023) / 1024;   // 98
    int beg = t * CH;
    int end = beg + CH; if (end > N_NODES) end = N_NODES;
    int s = 0;
    for (int i = beg; i < end; ++i) s += counts[i];
    lds[t] = s;
    __syncthreads();
    for (int off = 1; off < 1024; off <<= 1) {
        int v = (t >= off) ? lds[t - off] : 0;
        __syncthreads();
        lds[t] += v;
        __syncthreads();
    }
    int base = lds[t] - s;   // exclusive prefix
    for (int i = beg; i < end; ++i) {
        int c = counts[i];
        row_start[i] = base;
        counts[i]    = base;   // cursor init
        base += c;
    }
    if (t == 0) row_start[N_NODES] = E_TOT;
}

__global__ void scatter_kernel(const int* __restrict__ ei, int* __restrict__ cursor,
                               int* __restrict__ csr_src) {
    int e = blockIdx.x * blockDim.x + threadIdx.x;
    if (e >= E_TOT) return;
    int src, dst;
    if (e < N_EDGES) { src = ei[e]; dst = ei[N_EDGES + e]; }
    else             { src = dst = e - N_EDGES; }
    int pos = atomicAdd(&cursor[dst], 1);
    csr_src[pos] = src;
}

// ---------------- GEMM: C[M,Nc] = A[M,K] @ B[K,Nc], fp32 ----------------
// BM=64, BN=64, BK=16, 256 threads, 4x4 per thread.

__global__ __launch_bounds__(256)
void gemm64(const float* __restrict__ A, const float* __restrict__ B,
            float* __restrict__ C, int M, int K, int Nc) {
    __shared__ float As[16][68];   // [k][row], padded stride 68 (16B-aligned rows, bank-spread)
    __shared__ float Bs[16][64];   // [k][col]
    int tid = threadIdx.x;
    int tx = tid & 15, ty = tid >> 4;
    int rowBase = blockIdx.x * 64;
    int colBase = blockIdx.y * 64;

    int arow = tid >> 2, acg = (tid & 3) * 4;     // A: 64 rows x 16 cols, float4 each
    int brow = tid >> 4, bcol = (tid & 15) * 4;   // B: 16 rows x 64 cols, float4 each

    float acc[4][4] = {};

    for (int k0 = 0; k0 < K; k0 += 16) {
        int gr = rowBase + arow;
        float4 av = make_float4(0.f, 0.f, 0.f, 0.f);
        if (gr < M) av = *reinterpret_cast<const float4*>(&A[(long long)gr * K + k0 + acg]);
        As[acg + 0][arow] = av.x;
        As[acg + 1][arow] = av.y;
        As[acg + 2][arow] = av.z;
        As[acg + 3][arow] = av.w;
        float4 bv = *reinterpret_cast<const float4*>(&B[(long long)(k0 + brow) * Nc + colBase + bcol]);
        *reinterpret_cast<float4*>(&Bs[brow][bcol]) = bv;
        __syncthreads();
#pragma unroll
        for (int k = 0; k < 16; ++k) {
            float4 a4 = *reinterpret_cast<const float4*>(&As[k][ty * 4]);
            float4 b4 = *reinterpret_cast<const float4*>(&Bs[k][tx * 4]);
            float a[4] = {a4.x, a4.y, a4.z, a4.w};
            float b[4] = {b4.x, b4.y, b4.z, b4.w};
#pragma unroll
            for (int i = 0; i < 4; ++i)
#pragma unroll
                for (int j = 0; j < 4; ++j) acc[i][j] += a[i] * b[j];
        }
        __syncthreads();
    }
#pragma unroll
    for (int i = 0; i < 4; ++i) {
        int r = rowBase + ty * 4 + i;
        if (r < M) {
            float4 o = make_float4(acc[i][0], acc[i][1], acc[i][2], acc[i][3]);
            *reinterpret_cast<float4*>(&C[(long long)r * Nc + colBase + tx * 4]) = o;
        }
    }
}

// ---------------- attention coefficients ----------------
// alpha_s[n,h] = dot(h[n,h,:], a_src[h,:]); same for alpha_d.

__global__ void coef_kernel(const float* __restrict__ feat, const float* __restrict__ a_src,
                            const float* __restrict__ a_dst, float* __restrict__ als,
                            float* __restrict__ ald, int H, int C) {
    int t = blockIdx.x * blockDim.x + threadIdx.x;
    if (t >= N_NODES * H) return;
    int n = t / H, h = t % H;
    const float* f  = feat + (long long)n * H * C + h * C;
    const float* as = a_src + h * C;
    const float* ad = a_dst + h * C;
    float s = 0.f, d = 0.f;
    for (int c = 0; c < C; ++c) { float v = f[c]; s += v * as[c]; d += v * ad[c]; }
    als[t] = s;
    ald[t] = d;
}

// ---------------- segment softmax (gather over CSR) ----------------
// stores UNNORMALIZED exp(e-m) into alpha_csr; denom_inv holds 1/(sum+eps).

__global__ void softmax_kernel(const int* __restrict__ row_start, const int* __restrict__ csr_src,
                               const float* __restrict__ als, const float* __restrict__ ald,
                               float* __restrict__ alpha_csr, float* __restrict__ denom_inv, int H) {
    int t = blockIdx.x * blockDim.x + threadIdx.x;
    if (t >= N_NODES * H) return;
    int n = t / H, h = t % H;
    int s0 = row_start[n], s1 = row_start[n + 1];
    float ad = ald[t];
    float m = -1e30f;
    for (int i = s0; i < s1; ++i) {
        float e = als[csr_src[i] * H + h] + ad;
        e = e > 0.f ? e : NEG_SLOPE * e;
        alpha_csr[(long long)i * H + h] = e;
        m = fmaxf(m, e);
    }
    float sum = 0.f;
    for (int i = s0; i < s1; ++i) {
        float ex = __expf(alpha_csr[(long long)i * H + h] - m);
        alpha_csr[(long long)i * H + h] = ex;
        sum += ex;
    }
    denom_inv[t] = 1.0f / (sum + 1e-16f);
}

// ---------------- aggregate: out[n,ch] = (sum_e alpha*feat[src,ch]) * inv + bias ----------------

__global__ void aggregate_kernel(const int* __restrict__ row_start, const int* __restrict__ csr_src,
                                 const float* __restrict__ alpha_csr, const float* __restrict__ denom_inv,
                                 const float* __restrict__ feat, const float* __restrict__ bias,
                                 float* __restrict__ outp, int H, int C, int doElu) {
    int n  = blockIdx.x;
    int ch = threadIdx.x;          // HC threads per block
    int HC = H * C;
    int h  = ch / C;
    int s0 = row_start[n], s1 = row_start[n + 1];
    float acc = 0.f;
    for (int i = s0; i < s1; ++i) {
        int src = csr_src[i];
        float w = alpha_csr[(long long)i * H + h];
        acc += w * feat[(long long)src * HC + ch];
    }
    float val = acc * denom_inv[n * H + h] + bias[ch];
    if (doElu) val = val > 0.f ? val : __expf(val) - 1.0f;
    outp[(long long)n * HC + ch] = val;
}

// ---------------- launch ----------------

extern "C" void kernel_launch(void* const* d_in, const int* in_sizes, int n_in,
                              void* d_out, int out_size, void* d_ws, size_t ws_size,
                              hipStream_t stream) {
    const float* x   = (const float*)d_in[0];
    const int*   ei  = (const int*)d_in[1];
    const float* W1  = (const float*)d_in[2];
    const float* as1 = (const float*)d_in[3];
    const float* ad1 = (const float*)d_in[4];
    const float* b1  = (const float*)d_in[5];
    const float* W2  = (const float*)d_in[6];
    const float* as2 = (const float*)d_in[7];
    const float* ad2 = (const float*)d_in[8];
    const float* b2  = (const float*)d_in[9];
    const float* W3  = (const float*)d_in[10];
    const float* as3 = (const float*)d_in[11];
    const float* ad3 = (const float*)d_in[12];
    const float* b3  = (const float*)d_in[13];
    float* out = (float*)d_out;

    // workspace carve-up (256B aligned)
    char* ws = (char*)d_ws;
    size_t off = 0;
    auto alloc = [&](size_t bytes) { void* p = ws + off; off = (off + bytes + 255) & ~(size_t)255; return p; };
    int*   row_start = (int*)  alloc((N_NODES + 1) * sizeof(int));
    int*   cursor    = (int*)  alloc(N_NODES * sizeof(int));
    int*   csr_src   = (int*)  alloc((size_t)E_TOT * sizeof(int));
    float* alpha_s   = (float*)alloc((size_t)N_NODES * 4 * sizeof(float));
    float* alpha_d   = (float*)alloc((size_t)N_NODES * 4 * sizeof(float));
    float* denom_inv = (float*)alloc((size_t)N_NODES * 4 * sizeof(float));
    float* alpha_csr = (float*)alloc((size_t)E_TOT * 4 * sizeof(float));
    float* featA     = (float*)alloc((size_t)N_NODES * HID * sizeof(float));
    float* featB     = (float*)alloc((size_t)N_NODES * HID * sizeof(float));

    const int TPB = 256;
    int edgeBlocks = (E_TOT + TPB - 1) / TPB;

    // CSR build (per call; graph is the same for all 3 layers)
    hipMemsetAsync(cursor, 0, N_NODES * sizeof(int), stream);
    count_kernel<<<edgeBlocks, TPB, 0, stream>>>(ei, cursor);
    scan_kernel<<<1, 1024, 0, stream>>>(cursor, row_start);
    scatter_kernel<<<edgeBlocks, TPB, 0, stream>>>(ei, cursor, csr_src);

    dim3 gemmGrid((N_NODES + 63) / 64, 2);
    int nh4Blocks = (N_NODES * 4 + TPB - 1) / TPB;
    int nh1Blocks = (N_NODES + TPB - 1) / TPB;

    // ---- layer 1: in=256 -> H=4,C=32 (concat 128), ELU
    gemm64<<<gemmGrid, TPB, 0, stream>>>(x, W1, featA, N_NODES, IN_DIM, HID);
    coef_kernel<<<nh4Blocks, TPB, 0, stream>>>(featA, as1, ad1, alpha_s, alpha_d, 4, 32);
    softmax_kernel<<<nh4Blocks, TPB, 0, stream>>>(row_start, csr_src, alpha_s, alpha_d, alpha_csr, denom_inv, 4);
    aggregate_kernel<<<N_NODES, HID, 0, stream>>>(row_start, csr_src, alpha_csr, denom_inv, featA, b1, featB, 4, 32, 1);

    // ---- layer 2: 128 -> H=4,C=32 (concat 128), ELU
    gemm64<<<gemmGrid, TPB, 0, stream>>>(featB, W2, featA, N_NODES, HID, HID);
    coef_kernel<<<nh4Blocks, TPB, 0, stream>>>(featA, as2, ad2, alpha_s, alpha_d, 4, 32);
    softmax_kernel<<<nh4Blocks, TPB, 0, stream>>>(row_start, csr_src, alpha_s, alpha_d, alpha_csr, denom_inv, 4);
    aggregate_kernel<<<N_NODES, HID, 0, stream>>>(row_start, csr_src, alpha_csr, denom_inv, featA, b2, featB, 4, 32, 1);

    // ---- layer 3: 128 -> H=1,C=64 (mean over 1 head = identity), +bias, no ELU
    dim3 gemmGrid3((N_NODES + 63) / 64, 1);
    gemm64<<<gemmGrid3, TPB, 0, stream>>>(featB, W3, featA, N_NODES, HID, OUT_DIM);
    coef_kernel<<<nh1Blocks, TPB, 0, stream>>>(featA, as3, ad3, alpha_s, alpha_d, 1, 64);
    softmax_kernel<<<nh1Blocks, TPB, 0, stream>>>(row_start, csr_src, alpha_s, alpha_d, alpha_csr, denom_inv, 1);
    aggregate_kernel<<<N_NODES, OUT_DIM, 0, stream>>>(row_start, csr_src, alpha_csr, denom_inv, featA, b3, out, 1, 64, 0);
}

// Round 3
// 1101.339 us; speedup vs baseline: 1.1952x; 1.1952x over previous
//
#include <hip/hip_runtime.h>
#include <math.h>

#define N_NODES 100000
#define N_EDGES 1600000
#define E_TOT   (N_EDGES + N_NODES)
#define IN_DIM  256
#define HID     128
#define OUT_DIM 64
#define NEG_SLOPE 0.2f

#define SCAN_CHUNK  1024
#define SCAN_BLOCKS ((N_NODES + SCAN_CHUNK - 1) / SCAN_CHUNK)   // 98

// ---------------- CSR build ----------------

__global__ void count_kernel(const int* __restrict__ ei, int* __restrict__ counts) {
    int e = blockIdx.x * blockDim.x + threadIdx.x;
    if (e >= E_TOT) return;
    int dst = (e < N_EDGES) ? ei[N_EDGES + e] : (e - N_EDGES);
    atomicAdd(&counts[dst], 1);
}

// level 1: per-block (1024-node chunk) sums
__global__ __launch_bounds__(256)
void partial_kernel(const int* __restrict__ counts, int* __restrict__ partials) {
    __shared__ int lds[256];
    int b = blockIdx.x, t = threadIdx.x;
    int base = b * SCAN_CHUNK + t * 4;
    int s = 0;
#pragma unroll
    for (int j = 0; j < 4; ++j) { int i = base + j; if (i < N_NODES) s += counts[i]; }
    lds[t] = s;
    __syncthreads();
    for (int off = 128; off > 0; off >>= 1) {
        if (t < off) lds[t] += lds[t + off];
        __syncthreads();
    }
    if (t == 0) partials[b] = lds[0];
}

// level 2: exclusive scan of the 98 partials (1 block)
__global__ __launch_bounds__(128)
void scan_partials_kernel(int* __restrict__ partials) {
    __shared__ int lds[128];
    int t = threadIdx.x;
    int v = (t < SCAN_BLOCKS) ? partials[t] : 0;
    lds[t] = v;
    __syncthreads();
    for (int off = 1; off < 128; off <<= 1) {
        int u = (t >= off) ? lds[t - off] : 0;
        __syncthreads();
        lds[t] += u;
        __syncthreads();
    }
    if (t < SCAN_BLOCKS) partials[t] = lds[t] - v;   // exclusive
}

// level 3: per-chunk exclusive scan + base; writes row_start, re-inits cursor
// (counts buffer) in place. Each element is read then written only by its
// owning thread -> no hazard.
__global__ __launch_bounds__(256)
void write_offsets_kernel(int* __restrict__ counts, int* __restrict__ row_start,
                          const int* __restrict__ partials) {
    __shared__ int lds[256];
    int b = blockIdx.x, t = threadIdx.x;
    int base = b * SCAN_CHUNK + t * 4;
    int c[4];
    int s = 0;
#pragma unroll
    for (int j = 0; j < 4; ++j) {
        int i = base + j;
        c[j] = (i < N_NODES) ? counts[i] : 0;
        s += c[j];
    }
    lds[t] = s;
    __syncthreads();
    for (int off = 1; off < 256; off <<= 1) {
        int u = (t >= off) ? lds[t - off] : 0;
        __syncthreads();
        lds[t] += u;
        __syncthreads();
    }
    int run = partials[b] + (lds[t] - s);
#pragma unroll
    for (int j = 0; j < 4; ++j) {
        int i = base + j;
        if (i < N_NODES) { row_start[i] = run; counts[i] = run; run += c[j]; }
    }
    if (b == 0 && t == 0) row_start[N_NODES] = E_TOT;
}

__global__ void scatter_kernel(const int* __restrict__ ei, int* __restrict__ cursor,
                               int* __restrict__ csr_src) {
    int e = blockIdx.x * blockDim.x + threadIdx.x;
    if (e >= E_TOT) return;
    int src, dst;
    if (e < N_EDGES) { src = ei[e]; dst = ei[N_EDGES + e]; }
    else             { src = dst = e - N_EDGES; }
    int pos = atomicAdd(&cursor[dst], 1);
    csr_src[pos] = src;
}

// ---------------- GEMM: C[M,Nc] = A[M,K] @ B[K,Nc], fp32 ----------------
// BM=64, BN=64, BK=16, 256 threads, 4x4 per thread.

__global__ __launch_bounds__(256)
void gemm64(const float* __restrict__ A, const float* __restrict__ B,
            float* __restrict__ C, int M, int K, int Nc) {
    __shared__ float As[16][68];
    __shared__ float Bs[16][64];
    int tid = threadIdx.x;
    int tx = tid & 15, ty = tid >> 4;
    int rowBase = blockIdx.x * 64;
    int colBase = blockIdx.y * 64;

    int arow = tid >> 2, acg = (tid & 3) * 4;
    int brow = tid >> 4, bcol = (tid & 15) * 4;

    float acc[4][4] = {};

    for (int k0 = 0; k0 < K; k0 += 16) {
        int gr = rowBase + arow;
        float4 av = make_float4(0.f, 0.f, 0.f, 0.f);
        if (gr < M) av = *reinterpret_cast<const float4*>(&A[(long long)gr * K + k0 + acg]);
        As[acg + 0][arow] = av.x;
        As[acg + 1][arow] = av.y;
        As[acg + 2][arow] = av.z;
        As[acg + 3][arow] = av.w;
        float4 bv = *reinterpret_cast<const float4*>(&B[(long long)(k0 + brow) * Nc + colBase + bcol]);
        *reinterpret_cast<float4*>(&Bs[brow][bcol]) = bv;
        __syncthreads();
#pragma unroll
        for (int k = 0; k < 16; ++k) {
            float4 a4 = *reinterpret_cast<const float4*>(&As[k][ty * 4]);
            float4 b4 = *reinterpret_cast<const float4*>(&Bs[k][tx * 4]);
            float a[4] = {a4.x, a4.y, a4.z, a4.w};
            float b[4] = {b4.x, b4.y, b4.z, b4.w};
#pragma unroll
            for (int i = 0; i < 4; ++i)
#pragma unroll
                for (int j = 0; j < 4; ++j) acc[i][j] += a[i] * b[j];
        }
        __syncthreads();
    }
#pragma unroll
    for (int i = 0; i < 4; ++i) {
        int r = rowBase + ty * 4 + i;
        if (r < M) {
            float4 o = make_float4(acc[i][0], acc[i][1], acc[i][2], acc[i][3]);
            *reinterpret_cast<float4*>(&C[(long long)r * Nc + colBase + tx * 4]) = o;
        }
    }
}

// ---------------- attention coefficients ----------------

__global__ void coef_kernel(const float* __restrict__ feat, const float* __restrict__ a_src,
                            const float* __restrict__ a_dst, float* __restrict__ als,
                            float* __restrict__ ald, int H, int C) {
    int t = blockIdx.x * blockDim.x + threadIdx.x;
    if (t >= N_NODES * H) return;
    int n = t / H, h = t % H;
    const float* f  = feat + (long long)n * H * C + h * C;
    const float* as = a_src + h * C;
    const float* ad = a_dst + h * C;
    float s = 0.f, d = 0.f;
    for (int c = 0; c < C; ++c) { float v = f[c]; s += v * as[c]; d += v * ad[c]; }
    als[t] = s;
    ald[t] = d;
}

// ---------------- segment softmax (gather over CSR) ----------------

__global__ void softmax_kernel(const int* __restrict__ row_start, const int* __restrict__ csr_src,
                               const float* __restrict__ als, const float* __restrict__ ald,
                               float* __restrict__ alpha_csr, float* __restrict__ denom_inv, int H) {
    int t = blockIdx.x * blockDim.x + threadIdx.x;
    if (t >= N_NODES * H) return;
    int n = t / H, h = t % H;
    int s0 = row_start[n], s1 = row_start[n + 1];
    float ad = ald[t];
    float m = -1e30f;
    for (int i = s0; i < s1; ++i) {
        float e = als[csr_src[i] * H + h] + ad;
        e = e > 0.f ? e : NEG_SLOPE * e;
        alpha_csr[(long long)i * H + h] = e;
        m = fmaxf(m, e);
    }
    float sum = 0.f;
    for (int i = s0; i < s1; ++i) {
        float ex = __expf(alpha_csr[(long long)i * H + h] - m);
        alpha_csr[(long long)i * H + h] = ex;
        sum += ex;
    }
    denom_inv[t] = 1.0f / (sum + 1e-16f);
}

// ---------------- aggregate ----------------

__global__ void aggregate_kernel(const int* __restrict__ row_start, const int* __restrict__ csr_src,
                                 const float* __restrict__ alpha_csr, const float* __restrict__ denom_inv,
                                 const float* __restrict__ feat, const float* __restrict__ bias,
                                 float* __restrict__ outp, int H, int C, int doElu) {
    int n  = blockIdx.x;
    int ch = threadIdx.x;
    int HC = H * C;
    int h  = ch / C;
    int s0 = row_start[n], s1 = row_start[n + 1];
    float acc = 0.f;
    for (int i = s0; i < s1; ++i) {
        int src = csr_src[i];
        float w = alpha_csr[(long long)i * H + h];
        acc += w * feat[(long long)src * HC + ch];
    }
    float val = acc * denom_inv[n * H + h] + bias[ch];
    if (doElu) val = val > 0.f ? val : __expf(val) - 1.0f;
    outp[(long long)n * HC + ch] = val;
}

// ---------------- launch ----------------

extern "C" void kernel_launch(void* const* d_in, const int* in_sizes, int n_in,
                              void* d_out, int out_size, void* d_ws, size_t ws_size,
                              hipStream_t stream) {
    const float* x   = (const float*)d_in[0];
    const int*   ei  = (const int*)d_in[1];
    const float* W1  = (const float*)d_in[2];
    const float* as1 = (const float*)d_in[3];
    const float* ad1 = (const float*)d_in[4];
    const float* b1  = (const float*)d_in[5];
    const float* W2  = (const float*)d_in[6];
    const float* as2 = (const float*)d_in[7];
    const float* ad2 = (const float*)d_in[8];
    const float* b2  = (const float*)d_in[9];
    const float* W3  = (const float*)d_in[10];
    const float* as3 = (const float*)d_in[11];
    const float* ad3 = (const float*)d_in[12];
    const float* b3  = (const float*)d_in[13];
    float* out = (float*)d_out;

    // workspace carve-up (256B aligned)
    char* ws = (char*)d_ws;
    size_t off = 0;
    auto alloc = [&](size_t bytes) { void* p = ws + off; off = (off + bytes + 255) & ~(size_t)255; return p; };
    int*   row_start = (int*)  alloc((N_NODES + 1) * sizeof(int));
    int*   cursor    = (int*)  alloc(N_NODES * sizeof(int));
    int*   partials  = (int*)  alloc(SCAN_BLOCKS * sizeof(int));
    int*   csr_src   = (int*)  alloc((size_t)E_TOT * sizeof(int));
    float* alpha_s   = (float*)alloc((size_t)N_NODES * 4 * sizeof(float));
    float* alpha_d   = (float*)alloc((size_t)N_NODES * 4 * sizeof(float));
    float* denom_inv = (float*)alloc((size_t)N_NODES * 4 * sizeof(float));
    float* alpha_csr = (float*)alloc((size_t)E_TOT * 4 * sizeof(float));
    float* featA     = (float*)alloc((size_t)N_NODES * HID * sizeof(float));
    float* featB     = (float*)alloc((size_t)N_NODES * HID * sizeof(float));

    const int TPB = 256;
    int edgeBlocks = (E_TOT + TPB - 1) / TPB;

    // CSR build
    hipMemsetAsync(cursor, 0, N_NODES * sizeof(int), stream);
    count_kernel<<<edgeBlocks, TPB, 0, stream>>>(ei, cursor);
    partial_kernel<<<SCAN_BLOCKS, 256, 0, stream>>>(cursor, partials);
    scan_partials_kernel<<<1, 128, 0, stream>>>(partials);
    write_offsets_kernel<<<SCAN_BLOCKS, 256, 0, stream>>>(cursor, row_start, partials);
    scatter_kernel<<<edgeBlocks, TPB, 0, stream>>>(ei, cursor, csr_src);

    dim3 gemmGrid((N_NODES + 63) / 64, 2);
    int nh4Blocks = (N_NODES * 4 + TPB - 1) / TPB;
    int nh1Blocks = (N_NODES + TPB - 1) / TPB;

    // ---- layer 1: in=256 -> H=4,C=32 (concat 128), ELU
    gemm64<<<gemmGrid, TPB, 0, stream>>>(x, W1, featA, N_NODES, IN_DIM, HID);
    coef_kernel<<<nh4Blocks, TPB, 0, stream>>>(featA, as1, ad1, alpha_s, alpha_d, 4, 32);
    softmax_kernel<<<nh4Blocks, TPB, 0, stream>>>(row_start, csr_src, alpha_s, alpha_d, alpha_csr, denom_inv, 4);
    aggregate_kernel<<<N_NODES, HID, 0, stream>>>(row_start, csr_src, alpha_csr, denom_inv, featA, b1, featB, 4, 32, 1);

    // ---- layer 2: 128 -> H=4,C=32 (concat 128), ELU
    gemm64<<<gemmGrid, TPB, 0, stream>>>(featB, W2, featA, N_NODES, HID, HID);
    coef_kernel<<<nh4Blocks, TPB, 0, stream>>>(featA, as2, ad2, alpha_s, alpha_d, 4, 32);
    softmax_kernel<<<nh4Blocks, TPB, 0, stream>>>(row_start, csr_src, alpha_s, alpha_d, alpha_csr, denom_inv, 4);
    aggregate_kernel<<<N_NODES, HID, 0, stream>>>(row_start, csr_src, alpha_csr, denom_inv, featA, b2, featB, 4, 32, 1);

    // ---- layer 3: 128 -> H=1,C=64, +bias, no ELU
    dim3 gemmGrid3((N_NODES + 63) / 64, 1);
    gemm64<<<gemmGrid3, TPB, 0, stream>>>(featB, W3, featA, N_NODES, HID, OUT_DIM);
    coef_kernel<<<nh1Blocks, TPB, 0, stream>>>(featA, as3, ad3, alpha_s, alpha_d, 1, 64);
    softmax_kernel<<<nh1Blocks, TPB, 0, stream>>>(row_start, csr_src, alpha_s, alpha_d, alpha_csr, denom_inv, 1);
    aggregate_kernel<<<N_NODES, OUT_DIM, 0, stream>>>(row_start, csr_src, alpha_csr, denom_inv, featA, b3, out, 1, 64, 0);
}

// Round 4
// 864.623 us; speedup vs baseline: 1.5224x; 1.2738x over previous
//
#include <hip/hip_runtime.h>
#include <hip/hip_fp16.h>
#include <math.h>

#define N_NODES 100000
#define N_EDGES 1600000
#define E_TOT   (N_EDGES + N_NODES)
#define IN_DIM  256
#define HID     128
#define OUT_DIM 64
#define NEG_SLOPE 0.2f

#define SCAN_CHUNK  1024
#define SCAN_BLOCKS ((N_NODES + SCAN_CHUNK - 1) / SCAN_CHUNK)   // 98

// ---------------- CSR build ----------------

__global__ void count_kernel(const int* __restrict__ ei, int* __restrict__ counts) {
    int e = blockIdx.x * blockDim.x + threadIdx.x;
    if (e >= E_TOT) return;
    int dst = (e < N_EDGES) ? ei[N_EDGES + e] : (e - N_EDGES);
    atomicAdd(&counts[dst], 1);
}

__global__ __launch_bounds__(256)
void partial_kernel(const int* __restrict__ counts, int* __restrict__ partials) {
    __shared__ int lds[256];
    int b = blockIdx.x, t = threadIdx.x;
    int base = b * SCAN_CHUNK + t * 4;
    int s = 0;
#pragma unroll
    for (int j = 0; j < 4; ++j) { int i = base + j; if (i < N_NODES) s += counts[i]; }
    lds[t] = s;
    __syncthreads();
    for (int off = 128; off > 0; off >>= 1) {
        if (t < off) lds[t] += lds[t + off];
        __syncthreads();
    }
    if (t == 0) partials[b] = lds[0];
}

__global__ __launch_bounds__(128)
void scan_partials_kernel(int* __restrict__ partials) {
    __shared__ int lds[128];
    int t = threadIdx.x;
    int v = (t < SCAN_BLOCKS) ? partials[t] : 0;
    lds[t] = v;
    __syncthreads();
    for (int off = 1; off < 128; off <<= 1) {
        int u = (t >= off) ? lds[t - off] : 0;
        __syncthreads();
        lds[t] += u;
        __syncthreads();
    }
    if (t < SCAN_BLOCKS) partials[t] = lds[t] - v;   // exclusive
}

__global__ __launch_bounds__(256)
void write_offsets_kernel(int* __restrict__ counts, int* __restrict__ row_start,
                          const int* __restrict__ partials) {
    __shared__ int lds[256];
    int b = blockIdx.x, t = threadIdx.x;
    int base = b * SCAN_CHUNK + t * 4;
    int c[4];
    int s = 0;
#pragma unroll
    for (int j = 0; j < 4; ++j) {
        int i = base + j;
        c[j] = (i < N_NODES) ? counts[i] : 0;
        s += c[j];
    }
    lds[t] = s;
    __syncthreads();
    for (int off = 1; off < 256; off <<= 1) {
        int u = (t >= off) ? lds[t - off] : 0;
        __syncthreads();
        lds[t] += u;
        __syncthreads();
    }
    int run = partials[b] + (lds[t] - s);
#pragma unroll
    for (int j = 0; j < 4; ++j) {
        int i = base + j;
        if (i < N_NODES) { row_start[i] = run; counts[i] = run; run += c[j]; }
    }
    if (b == 0 && t == 0) row_start[N_NODES] = E_TOT;
}

__global__ void scatter_kernel(const int* __restrict__ ei, int* __restrict__ cursor,
                               int* __restrict__ csr_src) {
    int e = blockIdx.x * blockDim.x + threadIdx.x;
    if (e >= E_TOT) return;
    int src, dst;
    if (e < N_EDGES) { src = ei[e]; dst = ei[N_EDGES + e]; }
    else             { src = dst = e - N_EDGES; }
    int pos = atomicAdd(&cursor[dst], 1);
    csr_src[pos] = src;
}

// ---------------- GEMM: C = A@B fp32; also emits fp16 copy of C ----------------
// BM=64, BN=64, BK=16, 256 threads, 4x4 per thread.

__global__ __launch_bounds__(256)
void gemm64(const float* __restrict__ A, const float* __restrict__ B,
            float* __restrict__ C, __half* __restrict__ Ch, int M, int K, int Nc) {
    __shared__ float As[16][68];
    __shared__ float Bs[16][64];
    int tid = threadIdx.x;
    int tx = tid & 15, ty = tid >> 4;
    int rowBase = blockIdx.x * 64;
    int colBase = blockIdx.y * 64;

    int arow = tid >> 2, acg = (tid & 3) * 4;
    int brow = tid >> 4, bcol = (tid & 15) * 4;

    float acc[4][4] = {};

    for (int k0 = 0; k0 < K; k0 += 16) {
        int gr = rowBase + arow;
        float4 av = make_float4(0.f, 0.f, 0.f, 0.f);
        if (gr < M) av = *reinterpret_cast<const float4*>(&A[(long long)gr * K + k0 + acg]);
        As[acg + 0][arow] = av.x;
        As[acg + 1][arow] = av.y;
        As[acg + 2][arow] = av.z;
        As[acg + 3][arow] = av.w;
        float4 bv = *reinterpret_cast<const float4*>(&B[(long long)(k0 + brow) * Nc + colBase + bcol]);
        *reinterpret_cast<float4*>(&Bs[brow][bcol]) = bv;
        __syncthreads();
#pragma unroll
        for (int k = 0; k < 16; ++k) {
            float4 a4 = *reinterpret_cast<const float4*>(&As[k][ty * 4]);
            float4 b4 = *reinterpret_cast<const float4*>(&Bs[k][tx * 4]);
            float a[4] = {a4.x, a4.y, a4.z, a4.w};
            float b[4] = {b4.x, b4.y, b4.z, b4.w};
#pragma unroll
            for (int i = 0; i < 4; ++i)
#pragma unroll
                for (int j = 0; j < 4; ++j) acc[i][j] += a[i] * b[j];
        }
        __syncthreads();
    }
#pragma unroll
    for (int i = 0; i < 4; ++i) {
        int r = rowBase + ty * 4 + i;
        if (r < M) {
            float4 o = make_float4(acc[i][0], acc[i][1], acc[i][2], acc[i][3]);
            *reinterpret_cast<float4*>(&C[(long long)r * Nc + colBase + tx * 4]) = o;
            __half2* hp = reinterpret_cast<__half2*>(&Ch[(long long)r * Nc + colBase + tx * 4]);
            hp[0] = __floats2half2_rn(o.x, o.y);
            hp[1] = __floats2half2_rn(o.z, o.w);
        }
    }
}

// ---------------- attention coefficients ----------------

__global__ void coef_kernel(const float* __restrict__ feat, const float* __restrict__ a_src,
                            const float* __restrict__ a_dst, float* __restrict__ als,
                            float* __restrict__ ald, int H, int C) {
    int t = blockIdx.x * blockDim.x + threadIdx.x;
    if (t >= N_NODES * H) return;
    int n = t / H, h = t % H;
    const float* f  = feat + (long long)n * H * C + h * C;
    const float* as = a_src + h * C;
    const float* ad = a_dst + h * C;
    float s = 0.f, d = 0.f;
    for (int c = 0; c < C; ++c) { float v = f[c]; s += v * as[c]; d += v * ad[c]; }
    als[t] = s;
    ald[t] = d;
}

// ---------------- segment softmax (gather over CSR), fp16 alpha store ----------------

__global__ void softmax_kernel(const int* __restrict__ row_start, const int* __restrict__ csr_src,
                               const float* __restrict__ als, const float* __restrict__ ald,
                               __half* __restrict__ alpha_csr, float* __restrict__ denom_inv, int H) {
    int t = blockIdx.x * blockDim.x + threadIdx.x;
    if (t >= N_NODES * H) return;
    int n = t / H, h = t % H;
    int s0 = row_start[n], s1 = row_start[n + 1];
    float ad = ald[t];
    float m = -1e30f;
    for (int i = s0; i < s1; ++i) {
        float e = als[csr_src[i] * H + h] + ad;
        e = e > 0.f ? e : NEG_SLOPE * e;
        alpha_csr[(long long)i * H + h] = __float2half(e);
        m = fmaxf(m, e);
    }
    float sum = 0.f;
    for (int i = s0; i < s1; ++i) {
        float e = __half2float(alpha_csr[(long long)i * H + h]);
        float ex = __expf(e - m);
        alpha_csr[(long long)i * H + h] = __float2half(ex);
        sum += ex;
    }
    denom_inv[t] = 1.0f / (sum + 1e-16f);
}

// ---------------- aggregate: fp16 gather, fp32 accumulate ----------------
// block = one node, HC/2 threads, 2 channels/thread (half2 loads).

template<int H, int C, bool ELU>
__global__ __launch_bounds__(H * C / 2)
void aggregate_h(const int* __restrict__ row_start, const int* __restrict__ csr_src,
                 const __half* __restrict__ alpha_csr, const float* __restrict__ denom_inv,
                 const __half* __restrict__ feat, const float* __restrict__ bias,
                 float* __restrict__ outp) {
    constexpr int HC = H * C;
    int n  = blockIdx.x;
    int t  = threadIdx.x;
    int ch = 2 * t;
    int h  = ch / C;
    int s0 = row_start[n], s1 = row_start[n + 1];
    float acc0 = 0.f, acc1 = 0.f;
    int i = s0;
    for (; i + 2 <= s1; i += 2) {
        int sA = csr_src[i], sB = csr_src[i + 1];
        float wA = __half2float(alpha_csr[(long long)i * H + h]);
        float wB = __half2float(alpha_csr[(long long)(i + 1) * H + h]);
        __half2 fA = *reinterpret_cast<const __half2*>(&feat[(long long)sA * HC + ch]);
        __half2 fB = *reinterpret_cast<const __half2*>(&feat[(long long)sB * HC + ch]);
        float2 a = __half22float2(fA);
        float2 b = __half22float2(fB);
        acc0 = fmaf(wA, a.x, acc0); acc1 = fmaf(wA, a.y, acc1);
        acc0 = fmaf(wB, b.x, acc0); acc1 = fmaf(wB, b.y, acc1);
    }
    if (i < s1) {
        int sA = csr_src[i];
        float wA = __half2float(alpha_csr[(long long)i * H + h]);
        __half2 fA = *reinterpret_cast<const __half2*>(&feat[(long long)sA * HC + ch]);
        float2 a = __half22float2(fA);
        acc0 = fmaf(wA, a.x, acc0); acc1 = fmaf(wA, a.y, acc1);
    }
    float dinv = denom_inv[n * H + h];
    float v0 = acc0 * dinv + bias[ch];
    float v1 = acc1 * dinv + bias[ch + 1];
    if (ELU) {
        v0 = v0 > 0.f ? v0 : __expf(v0) - 1.0f;
        v1 = v1 > 0.f ? v1 : __expf(v1) - 1.0f;
    }
    *reinterpret_cast<float2*>(&outp[(long long)n * HC + ch]) = make_float2(v0, v1);
}

// ---------------- launch ----------------

extern "C" void kernel_launch(void* const* d_in, const int* in_sizes, int n_in,
                              void* d_out, int out_size, void* d_ws, size_t ws_size,
                              hipStream_t stream) {
    const float* x   = (const float*)d_in[0];
    const int*   ei  = (const int*)d_in[1];
    const float* W1  = (const float*)d_in[2];
    const float* as1 = (const float*)d_in[3];
    const float* ad1 = (const float*)d_in[4];
    const float* b1  = (const float*)d_in[5];
    const float* W2  = (const float*)d_in[6];
    const float* as2 = (const float*)d_in[7];
    const float* ad2 = (const float*)d_in[8];
    const float* b2  = (const float*)d_in[9];
    const float* W3  = (const float*)d_in[10];
    const float* as3 = (const float*)d_in[11];
    const float* ad3 = (const float*)d_in[12];
    const float* b3  = (const float*)d_in[13];
    float* out = (float*)d_out;

    // workspace carve-up (256B aligned)
    char* ws = (char*)d_ws;
    size_t off = 0;
    auto alloc = [&](size_t bytes) { void* p = ws + off; off = (off + bytes + 255) & ~(size_t)255; return p; };
    int*    row_start = (int*)   alloc((N_NODES + 1) * sizeof(int));
    int*    cursor    = (int*)   alloc(N_NODES * sizeof(int));
    int*    partials  = (int*)   alloc(SCAN_BLOCKS * sizeof(int));
    int*    csr_src   = (int*)   alloc((size_t)E_TOT * sizeof(int));
    float*  alpha_s   = (float*) alloc((size_t)N_NODES * 4 * sizeof(float));
    float*  alpha_d   = (float*) alloc((size_t)N_NODES * 4 * sizeof(float));
    float*  denom_inv = (float*) alloc((size_t)N_NODES * 4 * sizeof(float));
    __half* alpha_csr = (__half*)alloc((size_t)E_TOT * 4 * sizeof(__half));
    float*  featA     = (float*) alloc((size_t)N_NODES * HID * sizeof(float));
    float*  featB     = (float*) alloc((size_t)N_NODES * HID * sizeof(float));
    __half* featA_h   = (__half*)alloc((size_t)N_NODES * HID * sizeof(__half));

    const int TPB = 256;
    int edgeBlocks = (E_TOT + TPB - 1) / TPB;

    // CSR build
    hipMemsetAsync(cursor, 0, N_NODES * sizeof(int), stream);
    count_kernel<<<edgeBlocks, TPB, 0, stream>>>(ei, cursor);
    partial_kernel<<<SCAN_BLOCKS, 256, 0, stream>>>(cursor, partials);
    scan_partials_kernel<<<1, 128, 0, stream>>>(partials);
    write_offsets_kernel<<<SCAN_BLOCKS, 256, 0, stream>>>(cursor, row_start, partials);
    scatter_kernel<<<edgeBlocks, TPB, 0, stream>>>(ei, cursor, csr_src);

    dim3 gemmGrid((N_NODES + 63) / 64, 2);
    int nh4Blocks = (N_NODES * 4 + TPB - 1) / TPB;
    int nh1Blocks = (N_NODES + TPB - 1) / TPB;

    // ---- layer 1: in=256 -> H=4,C=32 (concat 128), ELU
    gemm64<<<gemmGrid, TPB, 0, stream>>>(x, W1, featA, featA_h, N_NODES, IN_DIM, HID);
    coef_kernel<<<nh4Blocks, TPB, 0, stream>>>(featA, as1, ad1, alpha_s, alpha_d, 4, 32);
    softmax_kernel<<<nh4Blocks, TPB, 0, stream>>>(row_start, csr_src, alpha_s, alpha_d, alpha_csr, denom_inv, 4);
    aggregate_h<4, 32, true><<<N_NODES, 64, 0, stream>>>(row_start, csr_src, alpha_csr, denom_inv, featA_h, b1, featB);

    // ---- layer 2: 128 -> H=4,C=32 (concat 128), ELU
    gemm64<<<gemmGrid, TPB, 0, stream>>>(featB, W2, featA, featA_h, N_NODES, HID, HID);
    coef_kernel<<<nh4Blocks, TPB, 0, stream>>>(featA, as2, ad2, alpha_s, alpha_d, 4, 32);
    softmax_kernel<<<nh4Blocks, TPB, 0, stream>>>(row_start, csr_src, alpha_s, alpha_d, alpha_csr, denom_inv, 4);
    aggregate_h<4, 32, true><<<N_NODES, 64, 0, stream>>>(row_start, csr_src, alpha_csr, denom_inv, featA_h, b2, featB);

    // ---- layer 3: 128 -> H=1,C=64, +bias, no ELU
    dim3 gemmGrid3((N_NODES + 63) / 64, 1);
    gemm64<<<gemmGrid3, TPB, 0, stream>>>(featB, W3, featA, featA_h, N_NODES, HID, OUT_DIM);
    coef_kernel<<<nh1Blocks, TPB, 0, stream>>>(featA, as3, ad3, alpha_s, alpha_d, 1, 64);
    softmax_kernel<<<nh1Blocks, TPB, 0, stream>>>(row_start, csr_src, alpha_s, alpha_d, alpha_csr, denom_inv, 1);
    aggregate_h<1, 64, false><<<N_NODES, 32, 0, stream>>>(row_start, csr_src, alpha_csr, denom_inv, featA_h, b3, out);
}

// Round 5
// 745.523 us; speedup vs baseline: 1.7656x; 1.1598x over previous
//
#include <hip/hip_runtime.h>
#include <hip/hip_fp16.h>
#include <math.h>

#define N_NODES 100000
#define N_EDGES 1600000
#define E_TOT   (N_EDGES + N_NODES)
#define IN_DIM  256
#define HID     128
#define OUT_DIM 64
#define NEG_SLOPE 0.2f

#define SCAN_CHUNK  1024
#define SCAN_BLOCKS ((N_NODES + SCAN_CHUNK - 1) / SCAN_CHUNK)   // 98

// ---------------- CSR build ----------------

__global__ void count_kernel(const int* __restrict__ ei, int* __restrict__ counts) {
    int e = blockIdx.x * blockDim.x + threadIdx.x;
    if (e >= E_TOT) return;
    int dst = (e < N_EDGES) ? ei[N_EDGES + e] : (e - N_EDGES);
    atomicAdd(&counts[dst], 1);
}

__global__ __launch_bounds__(256)
void partial_kernel(const int* __restrict__ counts, int* __restrict__ partials) {
    __shared__ int lds[256];
    int b = blockIdx.x, t = threadIdx.x;
    int base = b * SCAN_CHUNK + t * 4;
    int s = 0;
#pragma unroll
    for (int j = 0; j < 4; ++j) { int i = base + j; if (i < N_NODES) s += counts[i]; }
    lds[t] = s;
    __syncthreads();
    for (int off = 128; off > 0; off >>= 1) {
        if (t < off) lds[t] += lds[t + off];
        __syncthreads();
    }
    if (t == 0) partials[b] = lds[0];
}

__global__ __launch_bounds__(128)
void scan_partials_kernel(int* __restrict__ partials) {
    __shared__ int lds[128];
    int t = threadIdx.x;
    int v = (t < SCAN_BLOCKS) ? partials[t] : 0;
    lds[t] = v;
    __syncthreads();
    for (int off = 1; off < 128; off <<= 1) {
        int u = (t >= off) ? lds[t - off] : 0;
        __syncthreads();
        lds[t] += u;
        __syncthreads();
    }
    if (t < SCAN_BLOCKS) partials[t] = lds[t] - v;   // exclusive
}

__global__ __launch_bounds__(256)
void write_offsets_kernel(int* __restrict__ counts, int* __restrict__ row_start,
                          const int* __restrict__ partials) {
    __shared__ int lds[256];
    int b = blockIdx.x, t = threadIdx.x;
    int base = b * SCAN_CHUNK + t * 4;
    int c[4];
    int s = 0;
#pragma unroll
    for (int j = 0; j < 4; ++j) {
        int i = base + j;
        c[j] = (i < N_NODES) ? counts[i] : 0;
        s += c[j];
    }
    lds[t] = s;
    __syncthreads();
    for (int off = 1; off < 256; off <<= 1) {
        int u = (t >= off) ? lds[t - off] : 0;
        __syncthreads();
        lds[t] += u;
        __syncthreads();
    }
    int run = partials[b] + (lds[t] - s);
#pragma unroll
    for (int j = 0; j < 4; ++j) {
        int i = base + j;
        if (i < N_NODES) { row_start[i] = run; counts[i] = run; run += c[j]; }
    }
    if (b == 0 && t == 0) row_start[N_NODES] = E_TOT;
}

__global__ void scatter_kernel(const int* __restrict__ ei, int* __restrict__ cursor,
                               int* __restrict__ csr_src) {
    int e = blockIdx.x * blockDim.x + threadIdx.x;
    if (e >= E_TOT) return;
    int src, dst;
    if (e < N_EDGES) { src = ei[e]; dst = ei[N_EDGES + e]; }
    else             { src = dst = e - N_EDGES; }
    int pos = atomicAdd(&cursor[dst], 1);
    csr_src[pos] = src;
}

// ---------------- GEMM: C = A@B fp32; also emits fp16 copy of C ----------------

__global__ __launch_bounds__(256)
void gemm64(const float* __restrict__ A, const float* __restrict__ B,
            float* __restrict__ C, __half* __restrict__ Ch, int M, int K, int Nc) {
    __shared__ float As[16][68];
    __shared__ float Bs[16][64];
    int tid = threadIdx.x;
    int tx = tid & 15, ty = tid >> 4;
    int rowBase = blockIdx.x * 64;
    int colBase = blockIdx.y * 64;

    int arow = tid >> 2, acg = (tid & 3) * 4;
    int brow = tid >> 4, bcol = (tid & 15) * 4;

    float acc[4][4] = {};

    for (int k0 = 0; k0 < K; k0 += 16) {
        int gr = rowBase + arow;
        float4 av = make_float4(0.f, 0.f, 0.f, 0.f);
        if (gr < M) av = *reinterpret_cast<const float4*>(&A[(long long)gr * K + k0 + acg]);
        As[acg + 0][arow] = av.x;
        As[acg + 1][arow] = av.y;
        As[acg + 2][arow] = av.z;
        As[acg + 3][arow] = av.w;
        float4 bv = *reinterpret_cast<const float4*>(&B[(long long)(k0 + brow) * Nc + colBase + bcol]);
        *reinterpret_cast<float4*>(&Bs[brow][bcol]) = bv;
        __syncthreads();
#pragma unroll
        for (int k = 0; k < 16; ++k) {
            float4 a4 = *reinterpret_cast<const float4*>(&As[k][ty * 4]);
            float4 b4 = *reinterpret_cast<const float4*>(&Bs[k][tx * 4]);
            float a[4] = {a4.x, a4.y, a4.z, a4.w};
            float b[4] = {b4.x, b4.y, b4.z, b4.w};
#pragma unroll
            for (int i = 0; i < 4; ++i)
#pragma unroll
                for (int j = 0; j < 4; ++j) acc[i][j] += a[i] * b[j];
        }
        __syncthreads();
    }
#pragma unroll
    for (int i = 0; i < 4; ++i) {
        int r = rowBase + ty * 4 + i;
        if (r < M) {
            float4 o = make_float4(acc[i][0], acc[i][1], acc[i][2], acc[i][3]);
            *reinterpret_cast<float4*>(&C[(long long)r * Nc + colBase + tx * 4]) = o;
            __half2* hp = reinterpret_cast<__half2*>(&Ch[(long long)r * Nc + colBase + tx * 4]);
            hp[0] = __floats2half2_rn(o.x, o.y);
            hp[1] = __floats2half2_rn(o.z, o.w);
        }
    }
}

// ---------------- attention coefficients ----------------

__global__ void coef_kernel(const float* __restrict__ feat, const float* __restrict__ a_src,
                            const float* __restrict__ a_dst, float* __restrict__ als,
                            float* __restrict__ ald, int H, int C) {
    int t = blockIdx.x * blockDim.x + threadIdx.x;
    if (t >= N_NODES * H) return;
    int n = t / H, h = t % H;
    const float* f  = feat + (long long)n * H * C + h * C;
    const float* as = a_src + h * C;
    const float* ad = a_dst + h * C;
    float s = 0.f, d = 0.f;
    for (int c = 0; c < C; ++c) { float v = f[c]; s += v * as[c]; d += v * ad[c]; }
    als[t] = s;
    ald[t] = d;
}

// ---------------- fused softmax + aggregate ----------------
// block = one node = one 64-lane wave.
// phase A: online (max,sum) per head over the segment (reads csr_src + als only)
// phase B: 64-edge chunks; lane t computes w=exp(e-m) into LDS, then all lanes
//          gather fp16 features and accumulate in fp32; scale by 1/(sum+eps).

template<int H, int C, bool ELU>
__global__ __launch_bounds__(64)
void aggregate_fused(const int* __restrict__ row_start, const int* __restrict__ csr_src,
                     const float* __restrict__ als, const float* __restrict__ ald,
                     const __half* __restrict__ feat, const float* __restrict__ bias,
                     float* __restrict__ outp) {
    constexpr int HC  = H * C;
    constexpr int CPT = HC / 64;   // channels per thread: 2 (l1/l2) or 1 (l3)
    __shared__ float wlds[64 * H];
    __shared__ int   srclds[64];

    int n = blockIdx.x;
    int t = threadIdx.x;
    int s0 = row_start[n], s1 = row_start[n + 1];

    float adh[H];
#pragma unroll
    for (int h = 0; h < H; ++h) adh[h] = ald[n * H + h];

    // ---- phase A: per-lane online softmax stats
    float m[H], s[H];
#pragma unroll
    for (int h = 0; h < H; ++h) { m[h] = -1e30f; s[h] = 0.f; }
    for (int i = s0 + t; i < s1; i += 64) {
        int src = csr_src[i];
#pragma unroll
        for (int h = 0; h < H; ++h) {
            float e = als[src * H + h] + adh[h];
            e = e > 0.f ? e : NEG_SLOPE * e;
            float M = fmaxf(m[h], e);
            s[h] = s[h] * __expf(m[h] - M) + __expf(e - M);
            m[h] = M;
        }
    }
    // butterfly merge across the wave
#pragma unroll
    for (int h = 0; h < H; ++h) {
        for (int off = 1; off < 64; off <<= 1) {
            float m2 = __shfl_xor(m[h], off);
            float s2 = __shfl_xor(s[h], off);
            float M  = fmaxf(m[h], m2);
            s[h] = s[h] * __expf(m[h] - M) + s2 * __expf(m2 - M);
            m[h] = M;
        }
    }
    float dinv[H];
#pragma unroll
    for (int h = 0; h < H; ++h) dinv[h] = 1.0f / (s[h] + 1e-16f);

    // ---- phase B: chunked weighted gather
    int ch = t * CPT;
    int hh = ch / C;
    float acc0 = 0.f, acc1 = 0.f;
    for (int base = s0; base < s1; base += 64) {
        int len = s1 - base; if (len > 64) len = 64;
        if (t < len) {
            int i = base + t;
            int src = csr_src[i];
            srclds[t] = src;
#pragma unroll
            for (int h = 0; h < H; ++h) {
                float e = als[src * H + h] + adh[h];
                e = e > 0.f ? e : NEG_SLOPE * e;
                wlds[t * H + h] = __expf(e - m[h]);
            }
        }
        __syncthreads();
        for (int k = 0; k < len; ++k) {
            int src = srclds[k];
            float w = wlds[k * H + hh];
            if constexpr (CPT == 2) {
                __half2 f = *reinterpret_cast<const __half2*>(&feat[(long long)src * HC + ch]);
                float2 a = __half22float2(f);
                acc0 = fmaf(w, a.x, acc0);
                acc1 = fmaf(w, a.y, acc1);
            } else {
                float a = __half2float(feat[(long long)src * HC + ch]);
                acc0 = fmaf(w, a, acc0);
            }
        }
        __syncthreads();
    }

    // ---- epilogue
    if constexpr (CPT == 2) {
        float v0 = acc0 * dinv[hh] + bias[ch];
        float v1 = acc1 * dinv[hh] + bias[ch + 1];
        if (ELU) {
            v0 = v0 > 0.f ? v0 : __expf(v0) - 1.0f;
            v1 = v1 > 0.f ? v1 : __expf(v1) - 1.0f;
        }
        *reinterpret_cast<float2*>(&outp[(long long)n * HC + ch]) = make_float2(v0, v1);
    } else {
        float v0 = acc0 * dinv[hh] + bias[ch];
        if (ELU) v0 = v0 > 0.f ? v0 : __expf(v0) - 1.0f;
        outp[(long long)n * HC + ch] = v0;
    }
}

// ---------------- launch ----------------

extern "C" void kernel_launch(void* const* d_in, const int* in_sizes, int n_in,
                              void* d_out, int out_size, void* d_ws, size_t ws_size,
                              hipStream_t stream) {
    const float* x   = (const float*)d_in[0];
    const int*   ei  = (const int*)d_in[1];
    const float* W1  = (const float*)d_in[2];
    const float* as1 = (const float*)d_in[3];
    const float* ad1 = (const float*)d_in[4];
    const float* b1  = (const float*)d_in[5];
    const float* W2  = (const float*)d_in[6];
    const float* as2 = (const float*)d_in[7];
    const float* ad2 = (const float*)d_in[8];
    const float* b2  = (const float*)d_in[9];
    const float* W3  = (const float*)d_in[10];
    const float* as3 = (const float*)d_in[11];
    const float* ad3 = (const float*)d_in[12];
    const float* b3  = (const float*)d_in[13];
    float* out = (float*)d_out;

    // workspace carve-up (256B aligned)
    char* ws = (char*)d_ws;
    size_t off = 0;
    auto alloc = [&](size_t bytes) { void* p = ws + off; off = (off + bytes + 255) & ~(size_t)255; return p; };
    int*    row_start = (int*)   alloc((N_NODES + 1) * sizeof(int));
    int*    cursor    = (int*)   alloc(N_NODES * sizeof(int));
    int*    partials  = (int*)   alloc(SCAN_BLOCKS * sizeof(int));
    int*    csr_src   = (int*)   alloc((size_t)E_TOT * sizeof(int));
    float*  alpha_s   = (float*) alloc((size_t)N_NODES * 4 * sizeof(float));
    float*  alpha_d   = (float*) alloc((size_t)N_NODES * 4 * sizeof(float));
    float*  featA     = (float*) alloc((size_t)N_NODES * HID * sizeof(float));
    float*  featB     = (float*) alloc((size_t)N_NODES * HID * sizeof(float));
    __half* featA_h   = (__half*)alloc((size_t)N_NODES * HID * sizeof(__half));

    const int TPB = 256;
    int edgeBlocks = (E_TOT + TPB - 1) / TPB;

    // CSR build
    hipMemsetAsync(cursor, 0, N_NODES * sizeof(int), stream);
    count_kernel<<<edgeBlocks, TPB, 0, stream>>>(ei, cursor);
    partial_kernel<<<SCAN_BLOCKS, 256, 0, stream>>>(cursor, partials);
    scan_partials_kernel<<<1, 128, 0, stream>>>(partials);
    write_offsets_kernel<<<SCAN_BLOCKS, 256, 0, stream>>>(cursor, row_start, partials);
    scatter_kernel<<<edgeBlocks, TPB, 0, stream>>>(ei, cursor, csr_src);

    dim3 gemmGrid((N_NODES + 63) / 64, 2);
    int nh4Blocks = (N_NODES * 4 + TPB - 1) / TPB;
    int nh1Blocks = (N_NODES + TPB - 1) / TPB;

    // ---- layer 1: in=256 -> H=4,C=32 (concat 128), ELU
    gemm64<<<gemmGrid, TPB, 0, stream>>>(x, W1, featA, featA_h, N_NODES, IN_DIM, HID);
    coef_kernel<<<nh4Blocks, TPB, 0, stream>>>(featA, as1, ad1, alpha_s, alpha_d, 4, 32);
    aggregate_fused<4, 32, true><<<N_NODES, 64, 0, stream>>>(row_start, csr_src, alpha_s, alpha_d, featA_h, b1, featB);

    // ---- layer 2: 128 -> H=4,C=32 (concat 128), ELU
    gemm64<<<gemmGrid, TPB, 0, stream>>>(featB, W2, featA, featA_h, N_NODES, HID, HID);
    coef_kernel<<<nh4Blocks, TPB, 0, stream>>>(featA, as2, ad2, alpha_s, alpha_d, 4, 32);
    aggregate_fused<4, 32, true><<<N_NODES, 64, 0, stream>>>(row_start, csr_src, alpha_s, alpha_d, featA_h, b2, featB);

    // ---- layer 3: 128 -> H=1,C=64, +bias, no ELU
    dim3 gemmGrid3((N_NODES + 63) / 64, 1);
    gemm64<<<gemmGrid3, TPB, 0, stream>>>(featB, W3, featA, featA_h, N_NODES, HID, OUT_DIM);
    coef_kernel<<<nh1Blocks, TPB, 0, stream>>>(featA, as3, ad3, alpha_s, alpha_d, 1, 64);
    aggregate_fused<1, 64, false><<<N_NODES, 64, 0, stream>>>(row_start, csr_src, alpha_s, alpha_d, featA_h, b3, out);
}

// Round 6
// 709.089 us; speedup vs baseline: 1.8563x; 1.0514x over previous
//
#include <hip/hip_runtime.h>
#include <hip/hip_fp16.h>
#include <math.h>

#define N_NODES 100000
#define N_EDGES 1600000
#define E_TOT   (N_EDGES + N_NODES)
#define IN_DIM  256
#define HID     128
#define OUT_DIM 64
#define NEG_SLOPE 0.2f

#define SCAN_CHUNK  1024
#define SCAN_BLOCKS ((N_NODES + SCAN_CHUNK - 1) / SCAN_CHUNK)   // 98

#define NXCD      8
#define PART_SZ   (N_NODES / NXCD)     // 12500 exactly
#define EDGE_GRPS 832                  // edge chunks; grid = EDGE_GRPS*8 blocks

// ---------------- CSR build (XCD-partitioned count & scatter) ----------------
// Block b handles edge-chunk (b>>3) and commits only dsts in partition (b&7):
// under round-robin block->XCD dispatch, all writers of a given cursor/csr_src
// range sit on ONE XCD, so lines accumulate in its L2 instead of ping-ponging
// (r5 profile: WRITE_SIZE 108MB for 6.8MB of data = 64B/store).

__global__ __launch_bounds__(256)
void count_part_kernel(const int* __restrict__ ei, int* __restrict__ counts) {
    int part = blockIdx.x & (NXCD - 1);
    int grp  = blockIdx.x >> 3;
    int lo = part * PART_SZ, hi = lo + PART_SZ;
    for (int e = grp * 256 + (int)threadIdx.x; e < E_TOT; e += EDGE_GRPS * 256) {
        int dst = (e < N_EDGES) ? ei[N_EDGES + e] : (e - N_EDGES);
        if (dst >= lo && dst < hi) atomicAdd(&counts[dst], 1);
    }
}

__global__ __launch_bounds__(256)
void scatter_part_kernel(const int* __restrict__ ei, int* __restrict__ cursor,
                         int* __restrict__ csr_src) {
    int part = blockIdx.x & (NXCD - 1);
    int grp  = blockIdx.x >> 3;
    int lo = part * PART_SZ, hi = lo + PART_SZ;
    for (int e = grp * 256 + (int)threadIdx.x; e < E_TOT; e += EDGE_GRPS * 256) {
        int src, dst;
        if (e < N_EDGES) { src = ei[e]; dst = ei[N_EDGES + e]; }
        else             { src = dst = e - N_EDGES; }
        if (dst >= lo && dst < hi) {
            int pos = atomicAdd(&cursor[dst], 1);
            csr_src[pos] = src;
        }
    }
}

__global__ __launch_bounds__(256)
void partial_kernel(const int* __restrict__ counts, int* __restrict__ partials) {
    __shared__ int lds[256];
    int b = blockIdx.x, t = threadIdx.x;
    int base = b * SCAN_CHUNK + t * 4;
    int s = 0;
#pragma unroll
    for (int j = 0; j < 4; ++j) { int i = base + j; if (i < N_NODES) s += counts[i]; }
    lds[t] = s;
    __syncthreads();
    for (int off = 128; off > 0; off >>= 1) {
        if (t < off) lds[t] += lds[t + off];
        __syncthreads();
    }
    if (t == 0) partials[b] = lds[0];
}

__global__ __launch_bounds__(128)
void scan_partials_kernel(int* __restrict__ partials) {
    __shared__ int lds[128];
    int t = threadIdx.x;
    int v = (t < SCAN_BLOCKS) ? partials[t] : 0;
    lds[t] = v;
    __syncthreads();
    for (int off = 1; off < 128; off <<= 1) {
        int u = (t >= off) ? lds[t - off] : 0;
        __syncthreads();
        lds[t] += u;
        __syncthreads();
    }
    if (t < SCAN_BLOCKS) partials[t] = lds[t] - v;   // exclusive
}

__global__ __launch_bounds__(256)
void write_offsets_kernel(int* __restrict__ counts, int* __restrict__ row_start,
                          const int* __restrict__ partials) {
    __shared__ int lds[256];
    int b = blockIdx.x, t = threadIdx.x;
    int base = b * SCAN_CHUNK + t * 4;
    int c[4];
    int s = 0;
#pragma unroll
    for (int j = 0; j < 4; ++j) {
        int i = base + j;
        c[j] = (i < N_NODES) ? counts[i] : 0;
        s += c[j];
    }
    lds[t] = s;
    __syncthreads();
    for (int off = 1; off < 256; off <<= 1) {
        int u = (t >= off) ? lds[t - off] : 0;
        __syncthreads();
        lds[t] += u;
        __syncthreads();
    }
    int run = partials[b] + (lds[t] - s);
#pragma unroll
    for (int j = 0; j < 4; ++j) {
        int i = base + j;
        if (i < N_NODES) { row_start[i] = run; counts[i] = run; run += c[j]; }
    }
    if (b == 0 && t == 0) row_start[N_NODES] = E_TOT;
}

// ---------------- GEMM: C = A@B fp32; also emits fp16 copy of C ----------------

__global__ __launch_bounds__(256)
void gemm64(const float* __restrict__ A, const float* __restrict__ B,
            float* __restrict__ C, __half* __restrict__ Ch, int M, int K, int Nc) {
    __shared__ float As[16][68];
    __shared__ float Bs[16][64];
    int tid = threadIdx.x;
    int tx = tid & 15, ty = tid >> 4;
    int rowBase = blockIdx.x * 64;
    int colBase = blockIdx.y * 64;

    int arow = tid >> 2, acg = (tid & 3) * 4;
    int brow = tid >> 4, bcol = (tid & 15) * 4;

    float acc[4][4] = {};

    for (int k0 = 0; k0 < K; k0 += 16) {
        int gr = rowBase + arow;
        float4 av = make_float4(0.f, 0.f, 0.f, 0.f);
        if (gr < M) av = *reinterpret_cast<const float4*>(&A[(long long)gr * K + k0 + acg]);
        As[acg + 0][arow] = av.x;
        As[acg + 1][arow] = av.y;
        As[acg + 2][arow] = av.z;
        As[acg + 3][arow] = av.w;
        float4 bv = *reinterpret_cast<const float4*>(&B[(long long)(k0 + brow) * Nc + colBase + bcol]);
        *reinterpret_cast<float4*>(&Bs[brow][bcol]) = bv;
        __syncthreads();
#pragma unroll
        for (int k = 0; k < 16; ++k) {
            float4 a4 = *reinterpret_cast<const float4*>(&As[k][ty * 4]);
            float4 b4 = *reinterpret_cast<const float4*>(&Bs[k][tx * 4]);
            float a[4] = {a4.x, a4.y, a4.z, a4.w};
            float b[4] = {b4.x, b4.y, b4.z, b4.w};
#pragma unroll
            for (int i = 0; i < 4; ++i)
#pragma unroll
                for (int j = 0; j < 4; ++j) acc[i][j] += a[i] * b[j];
        }
        __syncthreads();
    }
#pragma unroll
    for (int i = 0; i < 4; ++i) {
        int r = rowBase + ty * 4 + i;
        if (r < M) {
            float4 o = make_float4(acc[i][0], acc[i][1], acc[i][2], acc[i][3]);
            *reinterpret_cast<float4*>(&C[(long long)r * Nc + colBase + tx * 4]) = o;
            __half2* hp = reinterpret_cast<__half2*>(&Ch[(long long)r * Nc + colBase + tx * 4]);
            hp[0] = __floats2half2_rn(o.x, o.y);
            hp[1] = __floats2half2_rn(o.z, o.w);
        }
    }
}

// ---------------- attention coefficients ----------------

__global__ void coef_kernel(const float* __restrict__ feat, const float* __restrict__ a_src,
                            const float* __restrict__ a_dst, float* __restrict__ als,
                            float* __restrict__ ald, int H, int C) {
    int t = blockIdx.x * blockDim.x + threadIdx.x;
    if (t >= N_NODES * H) return;
    int n = t / H, h = t % H;
    const float* f  = feat + (long long)n * H * C + h * C;
    const float* as = a_src + h * C;
    const float* ad = a_dst + h * C;
    float s = 0.f, d = 0.f;
    for (int c = 0; c < C; ++c) { float v = f[c]; s += v * as[c]; d += v * ad[c]; }
    als[t] = s;
    ald[t] = d;
}

// ---------------- fused softmax + aggregate (r5 structure, unchanged) ----------------

template<int H, int C, bool ELU>
__global__ __launch_bounds__(64)
void aggregate_fused(const int* __restrict__ row_start, const int* __restrict__ csr_src,
                     const float* __restrict__ als, const float* __restrict__ ald,
                     const __half* __restrict__ feat, const float* __restrict__ bias,
                     float* __restrict__ outp) {
    constexpr int HC  = H * C;
    constexpr int CPT = HC / 64;
    __shared__ float wlds[64 * H];
    __shared__ int   srclds[64];

    int n = blockIdx.x;
    int t = threadIdx.x;
    int s0 = row_start[n], s1 = row_start[n + 1];

    float adh[H];
#pragma unroll
    for (int h = 0; h < H; ++h) adh[h] = ald[n * H + h];

    float m[H], s[H];
#pragma unroll
    for (int h = 0; h < H; ++h) { m[h] = -1e30f; s[h] = 0.f; }
    for (int i = s0 + t; i < s1; i += 64) {
        int src = csr_src[i];
#pragma unroll
        for (int h = 0; h < H; ++h) {
            float e = als[src * H + h] + adh[h];
            e = e > 0.f ? e : NEG_SLOPE * e;
            float M = fmaxf(m[h], e);
            s[h] = s[h] * __expf(m[h] - M) + __expf(e - M);
            m[h] = M;
        }
    }
#pragma unroll
    for (int h = 0; h < H; ++h) {
        for (int off = 1; off < 64; off <<= 1) {
            float m2 = __shfl_xor(m[h], off);
            float s2 = __shfl_xor(s[h], off);
            float M  = fmaxf(m[h], m2);
            s[h] = s[h] * __expf(m[h] - M) + s2 * __expf(m2 - M);
            m[h] = M;
        }
    }
    float dinv[H];
#pragma unroll
    for (int h = 0; h < H; ++h) dinv[h] = 1.0f / (s[h] + 1e-16f);

    int ch = t * CPT;
    int hh = ch / C;
    float acc0 = 0.f, acc1 = 0.f;
    for (int base = s0; base < s1; base += 64) {
        int len = s1 - base; if (len > 64) len = 64;
        if (t < len) {
            int i = base + t;
            int src = csr_src[i];
            srclds[t] = src;
#pragma unroll
            for (int h = 0; h < H; ++h) {
                float e = als[src * H + h] + adh[h];
                e = e > 0.f ? e : NEG_SLOPE * e;
                wlds[t * H + h] = __expf(e - m[h]);
            }
        }
        __syncthreads();
        for (int k = 0; k < len; ++k) {
            int src = srclds[k];
            float w = wlds[k * H + hh];
            if constexpr (CPT == 2) {
                __half2 f = *reinterpret_cast<const __half2*>(&feat[(long long)src * HC + ch]);
                float2 a = __half22float2(f);
                acc0 = fmaf(w, a.x, acc0);
                acc1 = fmaf(w, a.y, acc1);
            } else {
                float a = __half2float(feat[(long long)src * HC + ch]);
                acc0 = fmaf(w, a, acc0);
            }
        }
        __syncthreads();
    }

    if constexpr (CPT == 2) {
        float v0 = acc0 * dinv[hh] + bias[ch];
        float v1 = acc1 * dinv[hh] + bias[ch + 1];
        if (ELU) {
            v0 = v0 > 0.f ? v0 : __expf(v0) - 1.0f;
            v1 = v1 > 0.f ? v1 : __expf(v1) - 1.0f;
        }
        *reinterpret_cast<float2*>(&outp[(long long)n * HC + ch]) = make_float2(v0, v1);
    } else {
        float v0 = acc0 * dinv[hh] + bias[ch];
        if (ELU) v0 = v0 > 0.f ? v0 : __expf(v0) - 1.0f;
        outp[(long long)n * HC + ch] = v0;
    }
}

// ---------------- launch ----------------

extern "C" void kernel_launch(void* const* d_in, const int* in_sizes, int n_in,
                              void* d_out, int out_size, void* d_ws, size_t ws_size,
                              hipStream_t stream) {
    const float* x   = (const float*)d_in[0];
    const int*   ei  = (const int*)d_in[1];
    const float* W1  = (const float*)d_in[2];
    const float* as1 = (const float*)d_in[3];
    const float* ad1 = (const float*)d_in[4];
    const float* b1  = (const float*)d_in[5];
    const float* W2  = (const float*)d_in[6];
    const float* as2 = (const float*)d_in[7];
    const float* ad2 = (const float*)d_in[8];
    const float* b2  = (const float*)d_in[9];
    const float* W3  = (const float*)d_in[10];
    const float* as3 = (const float*)d_in[11];
    const float* ad3 = (const float*)d_in[12];
    const float* b3  = (const float*)d_in[13];
    float* out = (float*)d_out;

    // workspace carve-up (256B aligned)
    char* ws = (char*)d_ws;
    size_t off = 0;
    auto alloc = [&](size_t bytes) { void* p = ws + off; off = (off + bytes + 255) & ~(size_t)255; return p; };
    int*    row_start = (int*)   alloc((N_NODES + 1) * sizeof(int));
    int*    cursor    = (int*)   alloc(N_NODES * sizeof(int));
    int*    partials  = (int*)   alloc(SCAN_BLOCKS * sizeof(int));
    int*    csr_src   = (int*)   alloc((size_t)E_TOT * sizeof(int));
    float*  alpha_s   = (float*) alloc((size_t)N_NODES * 4 * sizeof(float));
    float*  alpha_d   = (float*) alloc((size_t)N_NODES * 4 * sizeof(float));
    float*  featA     = (float*) alloc((size_t)N_NODES * HID * sizeof(float));
    float*  featB     = (float*) alloc((size_t)N_NODES * HID * sizeof(float));
    __half* featA_h   = (__half*)alloc((size_t)N_NODES * HID * sizeof(__half));

    const int TPB = 256;

    // CSR build (XCD-partitioned)
    hipMemsetAsync(cursor, 0, N_NODES * sizeof(int), stream);
    count_part_kernel<<<EDGE_GRPS * NXCD, TPB, 0, stream>>>(ei, cursor);
    partial_kernel<<<SCAN_BLOCKS, 256, 0, stream>>>(cursor, partials);
    scan_partials_kernel<<<1, 128, 0, stream>>>(partials);
    write_offsets_kernel<<<SCAN_BLOCKS, 256, 0, stream>>>(cursor, row_start, partials);
    scatter_part_kernel<<<EDGE_GRPS * NXCD, TPB, 0, stream>>>(ei, cursor, csr_src);

    dim3 gemmGrid((N_NODES + 63) / 64, 2);
    int nh4Blocks = (N_NODES * 4 + TPB - 1) / TPB;
    int nh1Blocks = (N_NODES + TPB - 1) / TPB;

    // ---- layer 1: in=256 -> H=4,C=32 (concat 128), ELU
    gemm64<<<gemmGrid, TPB, 0, stream>>>(x, W1, featA, featA_h, N_NODES, IN_DIM, HID);
    coef_kernel<<<nh4Blocks, TPB, 0, stream>>>(featA, as1, ad1, alpha_s, alpha_d, 4, 32);
    aggregate_fused<4, 32, true><<<N_NODES, 64, 0, stream>>>(row_start, csr_src, alpha_s, alpha_d, featA_h, b1, featB);

    // ---- layer 2: 128 -> H=4,C=32 (concat 128), ELU
    gemm64<<<gemmGrid, TPB, 0, stream>>>(featB, W2, featA, featA_h, N_NODES, HID, HID);
    coef_kernel<<<nh4Blocks, TPB, 0, stream>>>(featA, as2, ad2, alpha_s, alpha_d, 4, 32);
    aggregate_fused<4, 32, true><<<N_NODES, 64, 0, stream>>>(row_start, csr_src, alpha_s, alpha_d, featA_h, b2, featB);

    // ---- layer 3: 128 -> H=1,C=64, +bias, no ELU
    dim3 gemmGrid3((N_NODES + 63) / 64, 1);
    gemm64<<<gemmGrid3, TPB, 0, stream>>>(featB, W3, featA, featA_h, N_NODES, HID, OUT_DIM);
    coef_kernel<<<nh1Blocks, TPB, 0, stream>>>(featA, as3, ad3, alpha_s, alpha_d, 1, 64);
    aggregate_fused<1, 64, false><<<N_NODES, 64, 0, stream>>>(row_start, csr_src, alpha_s, alpha_d, featA_h, b3, out);
}

// Round 7
// 705.501 us; speedup vs baseline: 1.8657x; 1.0051x over previous
//
#include <hip/hip_runtime.h>
#include <hip/hip_fp16.h>
#include <math.h>

#define N_NODES 100000
#define N_EDGES 1600000
#define E_TOT   (N_EDGES + N_NODES)
#define IN_DIM  256
#define HID     128
#define OUT_DIM 64
#define NEG_SLOPE 0.2f

#define SCAN_CHUNK  1024
#define SCAN_BLOCKS ((N_NODES + SCAN_CHUNK - 1) / SCAN_CHUNK)   // 98

#define NXCD      8
#define PART_SZ   (N_NODES / NXCD)     // 12500 exactly
#define EDGE_GRPS 832                  // edge chunks; grid = EDGE_GRPS*8 blocks

// ---------------- CSR build (XCD-partitioned count & scatter) ----------------
// Block b handles edge-chunk (b>>3) and commits only dsts in partition (b&7):
// keeps each cursor/csr_src range's writers on ONE XCD so L2 lines fill
// before writeback (r5->r6: scatter WRITE_SIZE 108MB -> out of top-5).

__global__ __launch_bounds__(256)
void count_part_kernel(const int* __restrict__ ei, int* __restrict__ counts) {
    int part = blockIdx.x & (NXCD - 1);
    int grp  = blockIdx.x >> 3;
    int lo = part * PART_SZ, hi = lo + PART_SZ;
    for (int e = grp * 256 + (int)threadIdx.x; e < E_TOT; e += EDGE_GRPS * 256) {
        int dst = (e < N_EDGES) ? ei[N_EDGES + e] : (e - N_EDGES);
        if (dst >= lo && dst < hi) atomicAdd(&counts[dst], 1);
    }
}

__global__ __launch_bounds__(256)
void scatter_part_kernel(const int* __restrict__ ei, int* __restrict__ cursor,
                         int* __restrict__ csr_src) {
    int part = blockIdx.x & (NXCD - 1);
    int grp  = blockIdx.x >> 3;
    int lo = part * PART_SZ, hi = lo + PART_SZ;
    for (int e = grp * 256 + (int)threadIdx.x; e < E_TOT; e += EDGE_GRPS * 256) {
        int src, dst;
        if (e < N_EDGES) { src = ei[e]; dst = ei[N_EDGES + e]; }
        else             { src = dst = e - N_EDGES; }
        if (dst >= lo && dst < hi) {
            int pos = atomicAdd(&cursor[dst], 1);
            csr_src[pos] = src;
        }
    }
}

__global__ __launch_bounds__(256)
void partial_kernel(const int* __restrict__ counts, int* __restrict__ partials) {
    __shared__ int lds[256];
    int b = blockIdx.x, t = threadIdx.x;
    int base = b * SCAN_CHUNK + t * 4;
    int s = 0;
#pragma unroll
    for (int j = 0; j < 4; ++j) { int i = base + j; if (i < N_NODES) s += counts[i]; }
    lds[t] = s;
    __syncthreads();
    for (int off = 128; off > 0; off >>= 1) {
        if (t < off) lds[t] += lds[t + off];
        __syncthreads();
    }
    if (t == 0) partials[b] = lds[0];
}

__global__ __launch_bounds__(128)
void scan_partials_kernel(int* __restrict__ partials) {
    __shared__ int lds[128];
    int t = threadIdx.x;
    int v = (t < SCAN_BLOCKS) ? partials[t] : 0;
    lds[t] = v;
    __syncthreads();
    for (int off = 1; off < 128; off <<= 1) {
        int u = (t >= off) ? lds[t - off] : 0;
        __syncthreads();
        lds[t] += u;
        __syncthreads();
    }
    if (t < SCAN_BLOCKS) partials[t] = lds[t] - v;   // exclusive
}

__global__ __launch_bounds__(256)
void write_offsets_kernel(int* __restrict__ counts, int* __restrict__ row_start,
                          const int* __restrict__ partials) {
    __shared__ int lds[256];
    int b = blockIdx.x, t = threadIdx.x;
    int base = b * SCAN_CHUNK + t * 4;
    int c[4];
    int s = 0;
#pragma unroll
    for (int j = 0; j < 4; ++j) {
        int i = base + j;
        c[j] = (i < N_NODES) ? counts[i] : 0;
        s += c[j];
    }
    lds[t] = s;
    __syncthreads();
    for (int off = 1; off < 256; off <<= 1) {
        int u = (t >= off) ? lds[t - off] : 0;
        __syncthreads();
        lds[t] += u;
        __syncthreads();
    }
    int run = partials[b] + (lds[t] - s);
#pragma unroll
    for (int j = 0; j < 4; ++j) {
        int i = base + j;
        if (i < N_NODES) { row_start[i] = run; counts[i] = run; run += c[j]; }
    }
    if (b == 0 && t == 0) row_start[N_NODES] = E_TOT;
}

// ---------------- GEMM: C = A@B fp32; also emits fp16 copy of C ----------------

__global__ __launch_bounds__(256)
void gemm64(const float* __restrict__ A, const float* __restrict__ B,
            float* __restrict__ C, __half* __restrict__ Ch, int M, int K, int Nc) {
    __shared__ float As[16][68];
    __shared__ float Bs[16][64];
    int tid = threadIdx.x;
    int tx = tid & 15, ty = tid >> 4;
    int rowBase = blockIdx.x * 64;
    int colBase = blockIdx.y * 64;

    int arow = tid >> 2, acg = (tid & 3) * 4;
    int brow = tid >> 4, bcol = (tid & 15) * 4;

    float acc[4][4] = {};

    for (int k0 = 0; k0 < K; k0 += 16) {
        int gr = rowBase + arow;
        float4 av = make_float4(0.f, 0.f, 0.f, 0.f);
        if (gr < M) av = *reinterpret_cast<const float4*>(&A[(long long)gr * K + k0 + acg]);
        As[acg + 0][arow] = av.x;
        As[acg + 1][arow] = av.y;
        As[acg + 2][arow] = av.z;
        As[acg + 3][arow] = av.w;
        float4 bv = *reinterpret_cast<const float4*>(&B[(long long)(k0 + brow) * Nc + colBase + bcol]);
        *reinterpret_cast<float4*>(&Bs[brow][bcol]) = bv;
        __syncthreads();
#pragma unroll
        for (int k = 0; k < 16; ++k) {
            float4 a4 = *reinterpret_cast<const float4*>(&As[k][ty * 4]);
            float4 b4 = *reinterpret_cast<const float4*>(&Bs[k][tx * 4]);
            float a[4] = {a4.x, a4.y, a4.z, a4.w};
            float b[4] = {b4.x, b4.y, b4.z, b4.w};
#pragma unroll
            for (int i = 0; i < 4; ++i)
#pragma unroll
                for (int j = 0; j < 4; ++j) acc[i][j] += a[i] * b[j];
        }
        __syncthreads();
    }
#pragma unroll
    for (int i = 0; i < 4; ++i) {
        int r = rowBase + ty * 4 + i;
        if (r < M) {
            float4 o = make_float4(acc[i][0], acc[i][1], acc[i][2], acc[i][3]);
            *reinterpret_cast<float4*>(&C[(long long)r * Nc + colBase + tx * 4]) = o;
            __half2* hp = reinterpret_cast<__half2*>(&Ch[(long long)r * Nc + colBase + tx * 4]);
            hp[0] = __floats2half2_rn(o.x, o.y);
            hp[1] = __floats2half2_rn(o.z, o.w);
        }
    }
}

// ---------------- attention coefficients ----------------

__global__ void coef_kernel(const float* __restrict__ feat, const float* __restrict__ a_src,
                            const float* __restrict__ a_dst, float* __restrict__ als,
                            float* __restrict__ ald, int H, int C) {
    int t = blockIdx.x * blockDim.x + threadIdx.x;
    if (t >= N_NODES * H) return;
    int n = t / H, h = t % H;
    const float* f  = feat + (long long)n * H * C + h * C;
    const float* as = a_src + h * C;
    const float* ad = a_dst + h * C;
    float s = 0.f, d = 0.f;
    for (int c = 0; c < C; ++c) { float v = f[c]; s += v * as[c]; d += v * ad[c]; }
    als[t] = s;
    ald[t] = d;
}

// ---------------- fused softmax + aggregate v2 ----------------
// r6 profile: k-loop was a serial {ds_read -> 64b mul -> dependent gather}
// chain, latency-bound. v2: srclds holds precomputed BYTE offsets, per-lane
// channel base is a char*, and the k-loop is unrolled 4x for 4 gathers in
// flight. FP accumulation order unchanged.

template<int H, int C, bool ELU>
__global__ __launch_bounds__(64)
void aggregate_fused(const int* __restrict__ row_start, const int* __restrict__ csr_src,
                     const float* __restrict__ als, const float* __restrict__ ald,
                     const __half* __restrict__ feat, const float* __restrict__ bias,
                     float* __restrict__ outp) {
    constexpr int HC  = H * C;
    constexpr int CPT = HC / 64;
    __shared__ float wlds[64 * H];
    __shared__ int   offlds[64];      // byte offsets: src * HC * 2

    int n = blockIdx.x;
    int t = threadIdx.x;
    int s0 = row_start[n], s1 = row_start[n + 1];

    float adh[H];
#pragma unroll
    for (int h = 0; h < H; ++h) adh[h] = ald[n * H + h];

    // ---- phase A: per-lane online softmax stats
    float m[H], s[H];
#pragma unroll
    for (int h = 0; h < H; ++h) { m[h] = -1e30f; s[h] = 0.f; }
    for (int i = s0 + t; i < s1; i += 64) {
        int src = csr_src[i];
#pragma unroll
        for (int h = 0; h < H; ++h) {
            float e = als[src * H + h] + adh[h];
            e = e > 0.f ? e : NEG_SLOPE * e;
            float M = fmaxf(m[h], e);
            s[h] = s[h] * __expf(m[h] - M) + __expf(e - M);
            m[h] = M;
        }
    }
#pragma unroll
    for (int h = 0; h < H; ++h) {
        for (int off = 1; off < 64; off <<= 1) {
            float m2 = __shfl_xor(m[h], off);
            float s2 = __shfl_xor(s[h], off);
            float M  = fmaxf(m[h], m2);
            s[h] = s[h] * __expf(m[h] - M) + s2 * __expf(m2 - M);
            m[h] = M;
        }
    }
    float dinv[H];
#pragma unroll
    for (int h = 0; h < H; ++h) dinv[h] = 1.0f / (s[h] + 1e-16f);

    // ---- phase B: chunked weighted gather (4x unrolled, byte-offset LDS)
    int ch = t * CPT;
    int hh = ch / C;
    const char* fbase = (const char*)feat + ch * 2;   // + per-edge byte offset
    float acc0 = 0.f, acc1 = 0.f;
    for (int base = s0; base < s1; base += 64) {
        int len = s1 - base; if (len > 64) len = 64;
        if (t < len) {
            int i = base + t;
            int src = csr_src[i];
            offlds[t] = src * (HC * 2);
#pragma unroll
            for (int h = 0; h < H; ++h) {
                float e = als[src * H + h] + adh[h];
                e = e > 0.f ? e : NEG_SLOPE * e;
                wlds[t * H + h] = __expf(e - m[h]);
            }
        }
        __syncthreads();
#pragma unroll 4
        for (int k = 0; k < len; ++k) {
            int off = offlds[k];
            float w = wlds[k * H + hh];
            if constexpr (CPT == 2) {
                __half2 f = *reinterpret_cast<const __half2*>(fbase + off);
                float2 a = __half22float2(f);
                acc0 = fmaf(w, a.x, acc0);
                acc1 = fmaf(w, a.y, acc1);
            } else {
                float a = __half2float(*reinterpret_cast<const __half*>(fbase + off));
                acc0 = fmaf(w, a, acc0);
            }
        }
        __syncthreads();
    }

    // ---- epilogue
    if constexpr (CPT == 2) {
        float v0 = acc0 * dinv[hh] + bias[ch];
        float v1 = acc1 * dinv[hh] + bias[ch + 1];
        if (ELU) {
            v0 = v0 > 0.f ? v0 : __expf(v0) - 1.0f;
            v1 = v1 > 0.f ? v1 : __expf(v1) - 1.0f;
        }
        *reinterpret_cast<float2*>(&outp[(long long)n * HC + ch]) = make_float2(v0, v1);
    } else {
        float v0 = acc0 * dinv[hh] + bias[ch];
        if (ELU) v0 = v0 > 0.f ? v0 : __expf(v0) - 1.0f;
        outp[(long long)n * HC + ch] = v0;
    }
}

// ---------------- launch ----------------

extern "C" void kernel_launch(void* const* d_in, const int* in_sizes, int n_in,
                              void* d_out, int out_size, void* d_ws, size_t ws_size,
                              hipStream_t stream) {
    const float* x   = (const float*)d_in[0];
    const int*   ei  = (const int*)d_in[1];
    const float* W1  = (const float*)d_in[2];
    const float* as1 = (const float*)d_in[3];
    const float* ad1 = (const float*)d_in[4];
    const float* b1  = (const float*)d_in[5];
    const float* W2  = (const float*)d_in[6];
    const float* as2 = (const float*)d_in[7];
    const float* ad2 = (const float*)d_in[8];
    const float* b2  = (const float*)d_in[9];
    const float* W3  = (const float*)d_in[10];
    const float* as3 = (const float*)d_in[11];
    const float* ad3 = (const float*)d_in[12];
    const float* b3  = (const float*)d_in[13];
    float* out = (float*)d_out;

    // workspace carve-up (256B aligned)
    char* ws = (char*)d_ws;
    size_t off = 0;
    auto alloc = [&](size_t bytes) { void* p = ws + off; off = (off + bytes + 255) & ~(size_t)255; return p; };
    int*    row_start = (int*)   alloc((N_NODES + 1) * sizeof(int));
    int*    cursor    = (int*)   alloc(N_NODES * sizeof(int));
    int*    partials  = (int*)   alloc(SCAN_BLOCKS * sizeof(int));
    int*    csr_src   = (int*)   alloc((size_t)E_TOT * sizeof(int));
    float*  alpha_s   = (float*) alloc((size_t)N_NODES * 4 * sizeof(float));
    float*  alpha_d   = (float*) alloc((size_t)N_NODES * 4 * sizeof(float));
    float*  featA     = (float*) alloc((size_t)N_NODES * HID * sizeof(float));
    float*  featB     = (float*) alloc((size_t)N_NODES * HID * sizeof(float));
    __half* featA_h   = (__half*)alloc((size_t)N_NODES * HID * sizeof(__half));

    const int TPB = 256;

    // CSR build (XCD-partitioned)
    hipMemsetAsync(cursor, 0, N_NODES * sizeof(int), stream);
    count_part_kernel<<<EDGE_GRPS * NXCD, TPB, 0, stream>>>(ei, cursor);
    partial_kernel<<<SCAN_BLOCKS, 256, 0, stream>>>(cursor, partials);
    scan_partials_kernel<<<1, 128, 0, stream>>>(partials);
    write_offsets_kernel<<<SCAN_BLOCKS, 256, 0, stream>>>(cursor, row_start, partials);
    scatter_part_kernel<<<EDGE_GRPS * NXCD, TPB, 0, stream>>>(ei, cursor, csr_src);

    dim3 gemmGrid((N_NODES + 63) / 64, 2);
    int nh4Blocks = (N_NODES * 4 + TPB - 1) / TPB;
    int nh1Blocks = (N_NODES + TPB - 1) / TPB;

    // ---- layer 1: in=256 -> H=4,C=32 (concat 128), ELU
    gemm64<<<gemmGrid, TPB, 0, stream>>>(x, W1, featA, featA_h, N_NODES, IN_DIM, HID);
    coef_kernel<<<nh4Blocks, TPB, 0, stream>>>(featA, as1, ad1, alpha_s, alpha_d, 4, 32);
    aggregate_fused<4, 32, true><<<N_NODES, 64, 0, stream>>>(row_start, csr_src, alpha_s, alpha_d, featA_h, b1, featB);

    // ---- layer 2: 128 -> H=4,C=32 (concat 128), ELU
    gemm64<<<gemmGrid, TPB, 0, stream>>>(featB, W2, featA, featA_h, N_NODES, HID, HID);
    coef_kernel<<<nh4Blocks, TPB, 0, stream>>>(featA, as2, ad2, alpha_s, alpha_d, 4, 32);
    aggregate_fused<4, 32, true><<<N_NODES, 64, 0, stream>>>(row_start, csr_src, alpha_s, alpha_d, featA_h, b2, featB);

    // ---- layer 3: 128 -> H=1,C=64, +bias, no ELU
    dim3 gemmGrid3((N_NODES + 63) / 64, 1);
    gemm64<<<gemmGrid3, TPB, 0, stream>>>(featB, W3, featA, featA_h, N_NODES, HID, OUT_DIM);
    coef_kernel<<<nh1Blocks, TPB, 0, stream>>>(featA, as3, ad3, alpha_s, alpha_d, 1, 64);
    aggregate_fused<1, 64, false><<<N_NODES, 64, 0, stream>>>(row_start, csr_src, alpha_s, alpha_d, featA_h, b3, out);
}